// Round 6
// baseline (45820.020 us; speedup 1.0000x reference)
//
#include <hip/hip_runtime.h>
#include <hip/hip_bf16.h>

// Persistent tile-owner decoder. B=2048, T=256, H=512, P=64, PD=32, AD=128, V=12.
// 256 blocks x 512 thr, 1 block/CU (157KB LDS) -> co-resident. Block bk:
//   GEMM tile: m=bk&15 (128 b-rows), n=bk>>4 (128 perm-cols); B-tile in LDS (once).
//   attention/head owner of b = bk*8 .. bk*8+7.
// Per step: phase1 GEMM(K=576=[h|x|ctx]) + fused cell (c in regs, shfl gate-gather)
//   -> h2 to xh[(t+1)&1]; gbar; phase2: head(t) + Uh-GEMM + Ws-recompute(MFMA from
//   bf16 parts) + score/softmax/ctx -> xh[(t+1)&1] cols 512:556; gbar.
// gbar = distributed per-block flag barrier (R5 post-mortem: single-counter
// atomicAdd serialized ~170ns x nblocks = ~43us/barrier; flags avoid all RMW
// contention). All-thread threadfence BEFORE publish closes the R5 store race.

typedef __attribute__((ext_vector_type(8))) short short8;
typedef __attribute__((ext_vector_type(4))) float floatx4;

#define DEV static __device__ __forceinline__
#define C2LE 2.885390082f    // 2*log2(e)
#define LOG2E 1.4426950409f
#define LN2 0.6931471806f

DEV unsigned short f2bf(float f) {
    unsigned int u = __float_as_uint(f);
    unsigned int r = (u + 0x7FFFu + ((u >> 16) & 1u)) >> 16;
    return (unsigned short)r;
}
DEV float bf2f(unsigned short u) { return __uint_as_float(((unsigned int)u) << 16); }
DEV float rcp_f(float x) { float r; asm("v_rcp_f32 %0, %1" : "=v"(r) : "v"(x)); return r; }
DEV float tanh_f(float x) { return 1.f - 2.f * rcp_f(1.f + exp2f(x * C2LE)); }
DEV float sigm(float x) { return rcp_f(1.f + exp2f(-x * LOG2E)); }

// ---------------- workspace layout (bytes) ----------------
#define OFF_XH0    ((size_t)0)          // bf16 [2048][576]: h(512)|x(12)|ctx(32)|pad0(20)
#define OFF_XH1    ((size_t)2359296)
#define OFF_C0     ((size_t)4718592)    // f32 [2048][512]
#define OFF_PARTS  ((size_t)8912896)    // bf16 [2048][64][32]
#define OFF_WBIG   ((size_t)17301504)   // bf16 [2048][576], perm row p=4j+g <- orig g*512+j
#define OFF_WSMALL ((size_t)19660800)   // bf16 [160][512]: Uw(128), betaw(32)
#define OFF_WW2    ((size_t)19824640)   // bf16 [128][32] = C2LE*Ww
#define OFF_BIAS   ((size_t)19832832)   // f32 [2048] b_ih+b_hh (orig order)
#define OFF_AVG    ((size_t)19841024)   // f32 [2048][64]
#define OFF_FLAGS  ((size_t)20365312)   // int flags[256*32], 128B stride per block

// distributed flag barrier: monotonic step counters, one 128B line per block
DEV void gbar(int* flags, int bk, int step) {
    __threadfence();                 // EVERY wave flushes its own stores (vmcnt drain + wb)
    __syncthreads();                 // all waves' fences complete
    if (threadIdx.x == 0)
        __hip_atomic_store(flags + bk * 32, step, __ATOMIC_RELAXED, __HIP_MEMORY_SCOPE_AGENT);
    if (threadIdx.x < 64) {          // wave 0 polls all 256 flags, 4 per lane
        int i0 = threadIdx.x * 4;
        for (;;) {
            int mn = 0x7fffffff;
#pragma unroll
            for (int q = 0; q < 4; ++q) {
                int v = __hip_atomic_load(flags + (i0 + q) * 32,
                                          __ATOMIC_RELAXED, __HIP_MEMORY_SCOPE_AGENT);
                mn = min(mn, v);
            }
            if (__all(mn >= step)) break;
            __builtin_amdgcn_s_sleep(4);
        }
        __threadfence();             // acquire: invalidate stale L1/L2 lines
    }
    __syncthreads();
}

__global__ void k_init(int* flags) {
    int i = blockIdx.x * 256 + threadIdx.x;
    if (i < 256 * 32) flags[i] = 0;
}

__global__ void k_avg(const float* __restrict__ img, float* __restrict__ avg) {
    int idx = blockIdx.x * 256 + threadIdx.x;
    int b = idx >> 6, p = idx & 63;
    const float* base = img + (size_t)b * 2048 + p;
    float s = 0.f;
#pragma unroll
    for (int k = 0; k < 32; ++k) s += base[k * 64];
    avg[idx] = s * (1.f / 32.f);
}

__global__ void k_prep(const float* __restrict__ Whh, const float* __restrict__ Wih,
                       const float* __restrict__ Uw, const float* __restrict__ betaw,
                       const float* __restrict__ Ww, const float* __restrict__ bih,
                       const float* __restrict__ bhh,
                       unsigned short* __restrict__ Wbig, unsigned short* __restrict__ Wsmall,
                       unsigned short* __restrict__ Ww2, float* __restrict__ bias_cat) {
    int p = blockIdx.x, tid = threadIdx.x;
    int g = p & 3, j = p >> 2, orig = g * 512 + j;
    for (int k = tid; k < 576; k += 256) {
        float v = 0.f;
        if (k < 512) v = Whh[(size_t)orig * 512 + k];
        else if (k < 556) v = Wih[(size_t)orig * 44 + (k - 512)];
        Wbig[(size_t)p * 576 + k] = f2bf(v);
    }
    if (p < 160) {
        for (int k = tid; k < 512; k += 256) {
            float v = (p < 128) ? Uw[(size_t)p * 512 + k] : betaw[(size_t)(p - 128) * 512 + k];
            Wsmall[(size_t)p * 512 + k] = f2bf(v);
        }
    }
    if (p < 128 && tid < 32) Ww2[p * 32 + tid] = f2bf(C2LE * Ww[p * 32 + tid]);
    if (tid == 0) bias_cat[orig] = bih[orig] + bhh[orig];
}

__global__ __launch_bounds__(512) void k_h0c0(const float* __restrict__ avg,
                                              const float* __restrict__ ihw, const float* __restrict__ ihb,
                                              const float* __restrict__ icw, const float* __restrict__ icb,
                                              unsigned short* __restrict__ xh0, unsigned short* __restrict__ xh1,
                                              float* __restrict__ c0) {
    __shared__ float avg_s[8][64];
    int b0 = blockIdx.x * 8, tid = threadIdx.x;
    for (int i = tid; i < 8 * 64; i += 512) avg_s[i >> 6][i & 63] = avg[b0 * 64 + i];
    __syncthreads();
    int j = tid;
    float w0[64];
#pragma unroll
    for (int p4 = 0; p4 < 16; ++p4) {
        float4 v = ((const float4*)(ihw + j * 64))[p4];
        w0[p4 * 4 + 0] = v.x; w0[p4 * 4 + 1] = v.y; w0[p4 * 4 + 2] = v.z; w0[p4 * 4 + 3] = v.w;
    }
    float bh = ihb[j];
#pragma unroll
    for (int bb = 0; bb < 8; ++bb) {
        float s = bh;
#pragma unroll
        for (int p = 0; p < 64; ++p) s += w0[p] * avg_s[bb][p];
        xh0[(size_t)(b0 + bb) * 576 + j] = f2bf(tanh_f(s));
        if (j < 20) {
            xh0[(size_t)(b0 + bb) * 576 + 556 + j] = 0;
            xh1[(size_t)(b0 + bb) * 576 + 556 + j] = 0;
        }
    }
#pragma unroll
    for (int p4 = 0; p4 < 16; ++p4) {
        float4 v = ((const float4*)(icw + j * 64))[p4];
        w0[p4 * 4 + 0] = v.x; w0[p4 * 4 + 1] = v.y; w0[p4 * 4 + 2] = v.z; w0[p4 * 4 + 3] = v.w;
    }
    float bc = icb[j];
#pragma unroll
    for (int bb = 0; bb < 8; ++bb) {
        float s = bc;
#pragma unroll
        for (int p = 0; p < 64; ++p) s += w0[p] * avg_s[bb][p];
        c0[(size_t)(b0 + bb) * 512 + j] = tanh_f(s);
    }
}

// parts_bf[b][p][k] = bf16(img[b][k][p])
__global__ __launch_bounds__(256) void k_parts(const float* __restrict__ img,
                                               unsigned short* __restrict__ parts_bf) {
    __shared__ float pl[64][33];
    int b = blockIdx.x, tid = threadIdx.x;
    const float* ib = img + (size_t)b * 2048;
    for (int i = tid; i < 2048; i += 256) pl[i & 63][i >> 6] = ib[i];
    __syncthreads();
    for (int i = tid; i < 2048; i += 256)
        parts_bf[(size_t)b * 2048 + i] = f2bf(pl[i >> 5][i & 31]);
}

__global__ __launch_bounds__(512, 2) void k_scan(
    unsigned short* __restrict__ xh0, unsigned short* __restrict__ xh1,
    const float* __restrict__ c0,
    const unsigned short* __restrict__ parts_bf,
    const unsigned short* __restrict__ Wsmall, const unsigned short* __restrict__ Wbig,
    const unsigned short* __restrict__ Ww2, const float* __restrict__ bias_cat,
    const float* __restrict__ Ub, const float* __restrict__ betab, const float* __restrict__ Wb,
    const float* __restrict__ vw,
    const float* __restrict__ label, const float* __restrict__ ow, const float* __restrict__ ob,
    float* __restrict__ out_alpha, float* __restrict__ out_logits,
    int* __restrict__ flags)
{
    __shared__ unsigned short Bw[128 * 584];   // 149.5 KB B-tile, stride-pad 8 halfwords
    __shared__ float uh_l[8][160];             // 5 KB
    __shared__ float al_l[8][64];              // 2 KB
    __shared__ float vw2_l[128];               // -2*vw
    __shared__ float bias_sl[128];             // [g][jl] slice

    const int tid = threadIdx.x, w = tid >> 6, lane = tid & 63;
    const int bk = blockIdx.x, mtile = bk & 15, ntile = bk >> 4;
    const int wm = w >> 2, wn = w & 3;

    // ---- stage B-tile into LDS (once) ----
    for (int i = tid; i < 128 * 72; i += 512) {
        int r = i / 72, c8 = (i % 72) * 8;
        *(short8*)&Bw[r * 584 + c8] = *(const short8*)(Wbig + (size_t)(ntile * 128 + r) * 576 + c8);
    }
    if (tid < 128) {
        vw2_l[tid] = -2.f * vw[tid];
        bias_sl[tid] = bias_cat[(tid >> 5) * 512 + ntile * 32 + (tid & 31)];
    }
    // ---- c registers: cell (b,j) = (mtile*128+wm*64+mf*16+(lane>>4)*4+r, ntile*32+wn*8+nf*4+(lane&3))
    float creg[32];
#pragma unroll
    for (int mf = 0; mf < 4; ++mf)
#pragma unroll
        for (int nf = 0; nf < 2; ++nf)
#pragma unroll
            for (int r = 0; r < 4; ++r) {
                int b = mtile * 128 + wm * 64 + mf * 16 + (lane >> 4) * 4 + r;
                int j = ntile * 32 + wn * 8 + nf * 4 + (lane & 3);
                creg[(mf * 2 + nf) * 4 + r] = c0[(size_t)b * 512 + j];
            }
    __syncthreads();
    float vwsum = 0.f;
#pragma unroll
    for (int d = 0; d < 128; ++d) vwsum += vw2_l[d];
    vwsum *= -0.5f;

    // ---------- phase 2: head(tt-1) + Uh + attention(tt) on buffer xb ----------
    auto phase2 = [&](int tt, unsigned short* xb, bool do_head, bool do_attn) {
        int b = bk * 8 + w;
        if (do_head) {
            const unsigned short* hp = xb + (size_t)b * 576;
            short8 hv = *(const short8*)(hp + lane * 8);
            float hf[8];
#pragma unroll
            for (int j = 0; j < 8; ++j) hf[j] = bf2f((unsigned short)hv[j]);
            float ov[12];
#pragma unroll
            for (int v = 0; v < 12; ++v) {
                const float* owr = ow + v * 512 + lane * 8;
                float4 o0 = *(const float4*)owr;
                float4 o1 = *(const float4*)(owr + 4);
                float p = hf[0] * o0.x + hf[1] * o0.y + hf[2] * o0.z + hf[3] * o0.w
                        + hf[4] * o1.x + hf[5] * o1.y + hf[6] * o1.z + hf[7] * o1.w;
#pragma unroll
                for (int o = 32; o; o >>= 1) p += __shfl_xor(p, o);
                ov[v] = p + ob[v];
            }
            float mx = ov[0];
#pragma unroll
            for (int v = 1; v < 12; ++v) mx = fmaxf(mx, ov[v]);
            float ss = 0.f;
#pragma unroll
            for (int v = 0; v < 12; ++v) ss += exp2f((ov[v] - mx) * LOG2E);
            float lse = mx + log2f(ss) * LN2;
#pragma unroll
            for (int v = 0; v < 12; ++v)
                if (lane == v) out_logits[((size_t)b * 256 + (tt - 1)) * 12 + v] = ov[v] - lse;
        }
        if (do_attn && w < 5) {
            // Uh[8][160] = h[8x512] @ Wsmall^T; waves 0..4 cover n in [32w, 32w+32)
            int mr = bk * 8 + (lane & 15); if (mr > 2047) mr = 2047;
            const unsigned short* Ap = xb + (size_t)mr * 576 + (lane >> 4) * 8;
            const unsigned short* Bp = Wsmall + (size_t)(w * 32 + (lane & 15)) * 512 + (lane >> 4) * 8;
            floatx4 u0 = {}, u1 = {};
#pragma unroll 4
            for (int k0 = 0; k0 < 512; k0 += 32) {
                short8 a = *(const short8*)(Ap + k0);
                u0 = __builtin_amdgcn_mfma_f32_16x16x32_bf16(a, *(const short8*)(Bp + k0), u0, 0, 0, 0);
                u1 = __builtin_amdgcn_mfma_f32_16x16x32_bf16(a, *(const short8*)(Bp + 16 * 512 + k0), u1, 0, 0, 0);
            }
            int r0 = (lane >> 4) * 4, cc = lane & 15;
            if (r0 < 8) {
#pragma unroll
                for (int q = 0; q < 2; ++q) {
                    int n = w * 32 + q * 16 + cc;
#pragma unroll
                    for (int r = 0; r < 4; ++r) {
                        float val = (q ? u1[r] : u0[r]);
                        uh_l[r0 + r][n] = (n < 128) ? C2LE * (val + Ub[n] + Wb[n])
                                                    : (val + betab[n - 128]);
                    }
                }
            }
        }
        __syncthreads();
        if (do_attn) {
            // Ws recompute (MFMA) + score + softmax + ctx; wave per b
            const unsigned short* pb = parts_bf + (size_t)b * 2048;
            short8 pa[4];
#pragma unroll
            for (int mt = 0; mt < 4; ++mt)
                pa[mt] = *(const short8*)(pb + ((lane & 15) + 16 * mt) * 32 + (lane >> 4) * 8);
            float sc[4][4] = {};
#pragma unroll
            for (int nt = 0; nt < 8; ++nt) {
                short8 wwf = *(const short8*)(Ww2 + (size_t)((lane & 15) + 16 * nt) * 32 + (lane >> 4) * 8);
                int d = nt * 16 + (lane & 15);
                float ud = uh_l[w][d];
                float v2 = vw2_l[d];
#pragma unroll
                for (int mt = 0; mt < 4; ++mt) {
                    floatx4 z = {};
                    floatx4 wsa = __builtin_amdgcn_mfma_f32_16x16x32_bf16(pa[mt], wwf, z, 0, 0, 0);
#pragma unroll
                    for (int r = 0; r < 4; ++r)
                        sc[mt][r] += v2 * rcp_f(1.f + exp2f(wsa[r] + ud));
                }
            }
            float mx = -1e30f;
#pragma unroll
            for (int mt = 0; mt < 4; ++mt)
#pragma unroll
                for (int r = 0; r < 4; ++r) {
                    float s = sc[mt][r];
                    s += __shfl_xor(s, 1); s += __shfl_xor(s, 2);
                    s += __shfl_xor(s, 4); s += __shfl_xor(s, 8);
                    s += vwsum;
                    sc[mt][r] = s;
                    mx = fmaxf(mx, s);
                }
            mx = fmaxf(mx, __shfl_xor(mx, 16));
            mx = fmaxf(mx, __shfl_xor(mx, 32));
            float ssum = 0.f;
            float av[4][4];
#pragma unroll
            for (int mt = 0; mt < 4; ++mt)
#pragma unroll
                for (int r = 0; r < 4; ++r) {
                    av[mt][r] = exp2f((sc[mt][r] - mx) * LOG2E);
                    ssum += av[mt][r];
                }
            ssum += __shfl_xor(ssum, 16);
            ssum += __shfl_xor(ssum, 32);
            float rs = rcp_f(ssum);
#pragma unroll
            for (int mt = 0; mt < 4; ++mt) {
                if ((lane & 15) == mt) {
                    float4 fv = make_float4(av[mt][0] * rs, av[mt][1] * rs, av[mt][2] * rs, av[mt][3] * rs);
                    int p0 = mt * 16 + (lane >> 4) * 4;
                    *(float4*)&out_alpha[((size_t)tt * 2048 + b) * 64 + p0] = fv;
                    *(float4*)&al_l[w][p0] = fv;
                }
            }
            // ctx = alpha @ parts, * beta -> xb cols 524:556; x_t -> 512:524
            int k = lane & 31, half = lane >> 5;
            float cp = 0.f;
#pragma unroll
            for (int p = 0; p < 32; ++p) {
                int pp = half * 32 + p;
                cp += al_l[w][pp] * bf2f(parts_bf[(size_t)b * 2048 + pp * 32 + k]);
            }
            cp += __shfl_xor(cp, 32);
            if (half == 0) {
                float beta = sigm(uh_l[w][128 + k]);
                xb[(size_t)b * 576 + 524 + k] = f2bf(cp * beta);
            }
            if (lane < 12)
                xb[(size_t)b * 576 + 512 + lane] = f2bf(label[((size_t)b * 256 + tt) * 12 + lane]);
        }
    };

    // ---------- phase 1: gates GEMM + fused cell ----------
    auto phase1 = [&](const unsigned short* xin, unsigned short* xout) {
        const unsigned short* Ap = xin + (size_t)(mtile * 128 + wm * 64 + (lane & 15)) * 576 + (lane >> 4) * 8;
        const unsigned short* Bb = &Bw[(wn * 32 + (lane & 15)) * 584 + (lane >> 4) * 8];
        floatx4 acc[4][2] = {};
#pragma unroll 3
        for (int kk = 0; kk < 18; ++kk) {
            int k0 = kk * 32;
            short8 b0 = *(const short8*)(Bb + k0);
            short8 b1 = *(const short8*)(Bb + 16 * 584 + k0);
#pragma unroll
            for (int mf = 0; mf < 4; ++mf) {
                short8 a = *(const short8*)(Ap + (size_t)mf * 16 * 576 + k0);
                acc[mf][0] = __builtin_amdgcn_mfma_f32_16x16x32_bf16(a, b0, acc[mf][0], 0, 0, 0);
                acc[mf][1] = __builtin_amdgcn_mfma_f32_16x16x32_bf16(a, b1, acc[mf][1], 0, 0, 0);
            }
        }
        int base = (lane & 48) | (4 * (lane & 3));
        int jl = wn * 8 + (lane & 3);
#pragma unroll
        for (int mf = 0; mf < 4; ++mf)
#pragma unroll
            for (int nf = 0; nf < 2; ++nf) {
#pragma unroll
                for (int r = 0; r < 4; ++r) {
                    float x = acc[mf][nf][r];
                    float g0 = __shfl(x, base + 0);
                    float g1 = __shfl(x, base + 1);
                    float g2 = __shfl(x, base + 2);
                    float g3 = __shfl(x, base + 3);
                    int jj = jl + nf * 4;
                    float gi = g0 + bias_sl[jj];
                    float gf = g1 + bias_sl[32 + jj];
                    float gg = g2 + bias_sl[64 + jj];
                    float go = g3 + bias_sl[96 + jj];
                    int ci = (mf * 2 + nf) * 4 + r;
                    float c2 = sigm(gf) * creg[ci] + sigm(gi) * tanh_f(gg);
                    creg[ci] = c2;
                    float h2 = sigm(go) * tanh_f(c2);
                    if (((lane >> 2) & 3) == 0) {
                        int bg = mtile * 128 + wm * 64 + mf * 16 + (lane >> 4) * 4 + r;
                        xout[(size_t)bg * 576 + ntile * 32 + jj] = f2bf(h2);
                    }
                }
            }
    };

    int bc = 0;
    phase2(0, xh0, false, true);
    gbar(flags, bk, ++bc);
    for (int t = 0; t < 256; ++t) {
        const unsigned short* xin = (t & 1) ? xh1 : xh0;
        unsigned short* xout = (t & 1) ? xh0 : xh1;
        phase1(xin, xout);
        gbar(flags, bk, ++bc);
        phase2(t + 1, xout, true, t < 255);
        if (t < 255) gbar(flags, bk, ++bc);
    }
}

extern "C" void kernel_launch(void* const* d_in, const int* in_sizes, int n_in,
                              void* d_out, int out_size, void* d_ws, size_t ws_size,
                              hipStream_t stream) {
    const float* img   = (const float*)d_in[0];
    const float* label = (const float*)d_in[1];
    const float* Ww    = (const float*)d_in[2];
    const float* Wb    = (const float*)d_in[3];
    const float* Uw    = (const float*)d_in[4];
    const float* Ub    = (const float*)d_in[5];
    const float* vw    = (const float*)d_in[6];
    // d_in[7] = vb (cancels in softmax)
    const float* betaw = (const float*)d_in[8];
    const float* betab = (const float*)d_in[9];
    const float* ihw   = (const float*)d_in[10];
    const float* ihb   = (const float*)d_in[11];
    const float* icw   = (const float*)d_in[12];
    const float* icb   = (const float*)d_in[13];
    const float* Wih   = (const float*)d_in[14];
    const float* Whh   = (const float*)d_in[15];
    const float* bih   = (const float*)d_in[16];
    const float* bhh   = (const float*)d_in[17];
    const float* ow    = (const float*)d_in[18];
    const float* ob    = (const float*)d_in[19];

    char* ws = (char*)d_ws;
    unsigned short* xh0      = (unsigned short*)(ws + OFF_XH0);
    unsigned short* xh1      = (unsigned short*)(ws + OFF_XH1);
    float*          c0       = (float*)(ws + OFF_C0);
    unsigned short* parts_bf = (unsigned short*)(ws + OFF_PARTS);
    unsigned short* Wbig     = (unsigned short*)(ws + OFF_WBIG);
    unsigned short* Wsmall   = (unsigned short*)(ws + OFF_WSMALL);
    unsigned short* Ww2      = (unsigned short*)(ws + OFF_WW2);
    float*          bias     = (float*)(ws + OFF_BIAS);
    float*          avg      = (float*)(ws + OFF_AVG);
    int*            flags    = (int*)(ws + OFF_FLAGS);

    float* out_logits = (float*)d_out;
    float* out_alpha  = out_logits + (size_t)2048 * 256 * 12;

    k_init<<<32, 256, 0, stream>>>(flags);
    k_avg<<<512, 256, 0, stream>>>(img, avg);
    k_prep<<<2048, 256, 0, stream>>>(Whh, Wih, Uw, betaw, Ww, bih, bhh, Wbig, Wsmall, Ww2, bias);
    k_h0c0<<<256, 512, 0, stream>>>(avg, ihw, ihb, icw, icb, xh0, xh1, c0);
    k_parts<<<2048, 256, 0, stream>>>(img, parts_bf);

    k_scan<<<256, 512, 0, stream>>>(xh0, xh1, c0, parts_bf, Wsmall, Wbig, Ww2, bias,
                                    Ub, betab, Wb, vw, label, ow, ob,
                                    out_alpha, out_logits, flags);
}

// Round 7
// 20372.913 us; speedup vs baseline: 2.2491x; 2.2491x over previous
//
#include <hip/hip_runtime.h>
#include <hip/hip_bf16.h>

// Persistent tile-owner decoder. B=2048, T=256, H=512, P=64, PD=32, AD=128, V=12.
// 256 blocks x 512 thr, 1 block/CU -> co-resident. GROUPED: mtile=bk>>4, ntile=bk&15.
// Group g = blocks [g*16, g*16+16) owns batch rows [g*128, g*128+128) END-TO-END:
//   phase1 of group writes h2 for exactly those rows; phase2 owners (b=bk*8..+8)
//   lie in the same rows. Groups NEVER communicate -> 16-arrival group barrier.
// gbar: per-wave vmcnt drain + syncthreads; lane0: release fence + store own flag;
// wave0 lanes 0..15 poll the group's 16 flag lines in parallel; lane0 acquire fence.
// (R6 post-mortem: 256-flag all-poll saturated fabric; all-thread fences 8x'd L2 ops.
//  R5 post-mortem: single-counter atomicAdd serialized 256 RMWs ~43us/barrier.)

typedef __attribute__((ext_vector_type(8))) short short8;
typedef __attribute__((ext_vector_type(4))) float floatx4;

#define DEV static __device__ __forceinline__
#define C2LE 2.885390082f    // 2*log2(e)
#define LOG2E 1.4426950409f
#define LN2 0.6931471806f

DEV unsigned short f2bf(float f) {
    unsigned int u = __float_as_uint(f);
    unsigned int r = (u + 0x7FFFu + ((u >> 16) & 1u)) >> 16;
    return (unsigned short)r;
}
DEV float bf2f(unsigned short u) { return __uint_as_float(((unsigned int)u) << 16); }
DEV float rcp_f(float x) { float r; asm("v_rcp_f32 %0, %1" : "=v"(r) : "v"(x)); return r; }
DEV float tanh_f(float x) { return 1.f - 2.f * rcp_f(1.f + exp2f(x * C2LE)); }
DEV float sigm(float x) { return rcp_f(1.f + exp2f(-x * LOG2E)); }

// ---------------- workspace layout (bytes) ----------------
#define OFF_XH0    ((size_t)0)          // bf16 [2048][576]: h(512)|x(12)|ctx(32)|pad0(20)
#define OFF_XH1    ((size_t)2359296)
#define OFF_C0     ((size_t)4718592)    // f32 [2048][512]
#define OFF_PARTS  ((size_t)8912896)    // bf16 [2048][64][32]
#define OFF_WBIG   ((size_t)17301504)   // bf16 [2048][576], perm row p=4j+g <- orig g*512+j
#define OFF_WSMALL ((size_t)19660800)   // bf16 [160][512]: Uw(128), betaw(32)
#define OFF_WW2    ((size_t)19824640)   // bf16 [128][32] = C2LE*Ww
#define OFF_BIAS   ((size_t)19832832)   // f32 [2048] b_ih+b_hh (orig order)
#define OFF_AVG    ((size_t)19841024)   // f32 [2048][64]
#define OFF_FLAGS  ((size_t)20365312)   // int flags[256*32], 128B stride per block

// group barrier: 16 blocks, per-block monotonic flag, 16-lane parallel poll
DEV void gbar(int* flags, int bk, int g16, int step) {
    asm volatile("s_waitcnt vmcnt(0)" ::: "memory");  // each wave drains its stores to L2
    __syncthreads();
    if (threadIdx.x < 64) {
        int lane = threadIdx.x;
        if (lane == 0) {
            __threadfence();  // release: wb L2 so other XCDs can see our rows
            __hip_atomic_store(flags + bk * 32, step, __ATOMIC_RELAXED, __HIP_MEMORY_SCOPE_AGENT);
        }
        for (;;) {
            int v = 0x7fffffff;
            if (lane < 16)
                v = __hip_atomic_load(flags + (g16 + lane) * 32,
                                      __ATOMIC_RELAXED, __HIP_MEMORY_SCOPE_AGENT);
            if (__all(v >= step)) break;
            __builtin_amdgcn_s_sleep(1);
        }
        if (lane == 0) __threadfence();  // acquire: inv L1/L2 before consuming
    }
    __syncthreads();
}

__global__ void k_init(int* flags) {
    int i = blockIdx.x * 256 + threadIdx.x;
    if (i < 256 * 32) flags[i] = 0;
}

__global__ void k_avg(const float* __restrict__ img, float* __restrict__ avg) {
    int idx = blockIdx.x * 256 + threadIdx.x;
    int b = idx >> 6, p = idx & 63;
    const float* base = img + (size_t)b * 2048 + p;
    float s = 0.f;
#pragma unroll
    for (int k = 0; k < 32; ++k) s += base[k * 64];
    avg[idx] = s * (1.f / 32.f);
}

__global__ void k_prep(const float* __restrict__ Whh, const float* __restrict__ Wih,
                       const float* __restrict__ Uw, const float* __restrict__ betaw,
                       const float* __restrict__ Ww, const float* __restrict__ bih,
                       const float* __restrict__ bhh,
                       unsigned short* __restrict__ Wbig, unsigned short* __restrict__ Wsmall,
                       unsigned short* __restrict__ Ww2, float* __restrict__ bias_cat) {
    int p = blockIdx.x, tid = threadIdx.x;
    int g = p & 3, j = p >> 2, orig = g * 512 + j;
    for (int k = tid; k < 576; k += 256) {
        float v = 0.f;
        if (k < 512) v = Whh[(size_t)orig * 512 + k];
        else if (k < 556) v = Wih[(size_t)orig * 44 + (k - 512)];
        Wbig[(size_t)p * 576 + k] = f2bf(v);
    }
    if (p < 160) {
        for (int k = tid; k < 512; k += 256) {
            float v = (p < 128) ? Uw[(size_t)p * 512 + k] : betaw[(size_t)(p - 128) * 512 + k];
            Wsmall[(size_t)p * 512 + k] = f2bf(v);
        }
    }
    if (p < 128 && tid < 32) Ww2[p * 32 + tid] = f2bf(C2LE * Ww[p * 32 + tid]);
    if (tid == 0) bias_cat[orig] = bih[orig] + bhh[orig];
}

__global__ __launch_bounds__(512) void k_h0c0(const float* __restrict__ avg,
                                              const float* __restrict__ ihw, const float* __restrict__ ihb,
                                              const float* __restrict__ icw, const float* __restrict__ icb,
                                              unsigned short* __restrict__ xh0, unsigned short* __restrict__ xh1,
                                              float* __restrict__ c0) {
    __shared__ float avg_s[8][64];
    int b0 = blockIdx.x * 8, tid = threadIdx.x;
    for (int i = tid; i < 8 * 64; i += 512) avg_s[i >> 6][i & 63] = avg[b0 * 64 + i];
    __syncthreads();
    int j = tid;
    float w0[64];
#pragma unroll
    for (int p4 = 0; p4 < 16; ++p4) {
        float4 v = ((const float4*)(ihw + j * 64))[p4];
        w0[p4 * 4 + 0] = v.x; w0[p4 * 4 + 1] = v.y; w0[p4 * 4 + 2] = v.z; w0[p4 * 4 + 3] = v.w;
    }
    float bh = ihb[j];
#pragma unroll
    for (int bb = 0; bb < 8; ++bb) {
        float s = bh;
#pragma unroll
        for (int p = 0; p < 64; ++p) s += w0[p] * avg_s[bb][p];
        xh0[(size_t)(b0 + bb) * 576 + j] = f2bf(tanh_f(s));
        if (j < 20) {
            xh0[(size_t)(b0 + bb) * 576 + 556 + j] = 0;
            xh1[(size_t)(b0 + bb) * 576 + 556 + j] = 0;
        }
    }
#pragma unroll
    for (int p4 = 0; p4 < 16; ++p4) {
        float4 v = ((const float4*)(icw + j * 64))[p4];
        w0[p4 * 4 + 0] = v.x; w0[p4 * 4 + 1] = v.y; w0[p4 * 4 + 2] = v.z; w0[p4 * 4 + 3] = v.w;
    }
    float bc = icb[j];
#pragma unroll
    for (int bb = 0; bb < 8; ++bb) {
        float s = bc;
#pragma unroll
        for (int p = 0; p < 64; ++p) s += w0[p] * avg_s[bb][p];
        c0[(size_t)(b0 + bb) * 512 + j] = tanh_f(s);
    }
}

// parts_bf[b][p][k] = bf16(img[b][k][p])
__global__ __launch_bounds__(256) void k_parts(const float* __restrict__ img,
                                               unsigned short* __restrict__ parts_bf) {
    __shared__ float pl[64][33];
    int b = blockIdx.x, tid = threadIdx.x;
    const float* ib = img + (size_t)b * 2048;
    for (int i = tid; i < 2048; i += 256) pl[i & 63][i >> 6] = ib[i];
    __syncthreads();
    for (int i = tid; i < 2048; i += 256)
        parts_bf[(size_t)b * 2048 + i] = f2bf(pl[i >> 5][i & 31]);
}

__global__ __launch_bounds__(512, 2) void k_scan(
    unsigned short* __restrict__ xh0, unsigned short* __restrict__ xh1,
    const float* __restrict__ c0,
    const unsigned short* __restrict__ parts_bf,
    const unsigned short* __restrict__ Wsmall, const unsigned short* __restrict__ Wbig,
    const unsigned short* __restrict__ Ww2, const float* __restrict__ bias_cat,
    const float* __restrict__ Ub, const float* __restrict__ betab, const float* __restrict__ Wb,
    const float* __restrict__ vw,
    const float* __restrict__ label, const float* __restrict__ ow, const float* __restrict__ ob,
    float* __restrict__ out_alpha, float* __restrict__ out_logits,
    int* __restrict__ flags)
{
    __shared__ unsigned short Bw[128 * 584];   // 149.5 KB B-tile, stride-pad 8 halfwords
    __shared__ float uh_l[8][160];             // 5 KB
    __shared__ float al_l[8][64];              // 2 KB
    __shared__ float vw2_l[128];               // -2*vw
    __shared__ float bias_sl[128];             // [g][jl] slice

    const int tid = threadIdx.x, w = tid >> 6, lane = tid & 63;
    const int bk = blockIdx.x;
    const int mtile = bk >> 4, ntile = bk & 15;   // GROUPED: group = mtile
    const int g16 = mtile * 16;                   // first block of my group
    const int wm = w >> 2, wn = w & 3;

    // ---- stage B-tile into LDS (once) ----
    for (int i = tid; i < 128 * 72; i += 512) {
        int r = i / 72, c8 = (i % 72) * 8;
        *(short8*)&Bw[r * 584 + c8] = *(const short8*)(Wbig + (size_t)(ntile * 128 + r) * 576 + c8);
    }
    if (tid < 128) {
        vw2_l[tid] = -2.f * vw[tid];
        bias_sl[tid] = bias_cat[(tid >> 5) * 512 + ntile * 32 + (tid & 31)];
    }
    // ---- c registers: cell (b,j) = (mtile*128+wm*64+mf*16+(lane>>4)*4+r, ntile*32+wn*8+nf*4+(lane&3))
    float creg[32];
#pragma unroll
    for (int mf = 0; mf < 4; ++mf)
#pragma unroll
        for (int nf = 0; nf < 2; ++nf)
#pragma unroll
            for (int r = 0; r < 4; ++r) {
                int b = mtile * 128 + wm * 64 + mf * 16 + (lane >> 4) * 4 + r;
                int j = ntile * 32 + wn * 8 + nf * 4 + (lane & 3);
                creg[(mf * 2 + nf) * 4 + r] = c0[(size_t)b * 512 + j];
            }
    __syncthreads();
    float vwsum = 0.f;
#pragma unroll
    for (int d = 0; d < 128; ++d) vwsum += vw2_l[d];
    vwsum *= -0.5f;

    // ---------- phase 2: head(tt-1) + Uh + attention(tt) on buffer xb ----------
    auto phase2 = [&](int tt, unsigned short* xb, bool do_head, bool do_attn) {
        int b = bk * 8 + w;
        if (do_head) {
            const unsigned short* hp = xb + (size_t)b * 576;
            short8 hv = *(const short8*)(hp + lane * 8);
            float hf[8];
#pragma unroll
            for (int j = 0; j < 8; ++j) hf[j] = bf2f((unsigned short)hv[j]);
            float ov[12];
#pragma unroll
            for (int v = 0; v < 12; ++v) {
                const float* owr = ow + v * 512 + lane * 8;
                float4 o0 = *(const float4*)owr;
                float4 o1 = *(const float4*)(owr + 4);
                float p = hf[0] * o0.x + hf[1] * o0.y + hf[2] * o0.z + hf[3] * o0.w
                        + hf[4] * o1.x + hf[5] * o1.y + hf[6] * o1.z + hf[7] * o1.w;
#pragma unroll
                for (int o = 32; o; o >>= 1) p += __shfl_xor(p, o);
                ov[v] = p + ob[v];
            }
            float mx = ov[0];
#pragma unroll
            for (int v = 1; v < 12; ++v) mx = fmaxf(mx, ov[v]);
            float ss = 0.f;
#pragma unroll
            for (int v = 0; v < 12; ++v) ss += exp2f((ov[v] - mx) * LOG2E);
            float lse = mx + log2f(ss) * LN2;
#pragma unroll
            for (int v = 0; v < 12; ++v)
                if (lane == v) out_logits[((size_t)b * 256 + (tt - 1)) * 12 + v] = ov[v] - lse;
        }
        if (do_attn && w < 5) {
            // Uh[8][160] = h[8x512] @ Wsmall^T; waves 0..4 cover n in [32w, 32w+32)
            int mr = bk * 8 + (lane & 15); if (mr > 2047) mr = 2047;
            const unsigned short* Ap = xb + (size_t)mr * 576 + (lane >> 4) * 8;
            const unsigned short* Bp = Wsmall + (size_t)(w * 32 + (lane & 15)) * 512 + (lane >> 4) * 8;
            floatx4 u0 = {}, u1 = {};
#pragma unroll 4
            for (int k0 = 0; k0 < 512; k0 += 32) {
                short8 a = *(const short8*)(Ap + k0);
                u0 = __builtin_amdgcn_mfma_f32_16x16x32_bf16(a, *(const short8*)(Bp + k0), u0, 0, 0, 0);
                u1 = __builtin_amdgcn_mfma_f32_16x16x32_bf16(a, *(const short8*)(Bp + 16 * 512 + k0), u1, 0, 0, 0);
            }
            int r0 = (lane >> 4) * 4, cc = lane & 15;
            if (r0 < 8) {
#pragma unroll
                for (int q = 0; q < 2; ++q) {
                    int n = w * 32 + q * 16 + cc;
#pragma unroll
                    for (int r = 0; r < 4; ++r) {
                        float val = (q ? u1[r] : u0[r]);
                        uh_l[r0 + r][n] = (n < 128) ? C2LE * (val + Ub[n] + Wb[n])
                                                    : (val + betab[n - 128]);
                    }
                }
            }
        }
        __syncthreads();
        if (do_attn) {
            // Ws recompute (MFMA) + score + softmax + ctx; wave per b
            const unsigned short* pb = parts_bf + (size_t)b * 2048;
            short8 pa[4];
#pragma unroll
            for (int mt = 0; mt < 4; ++mt)
                pa[mt] = *(const short8*)(pb + ((lane & 15) + 16 * mt) * 32 + (lane >> 4) * 8);
            float sc[4][4] = {};
#pragma unroll
            for (int nt = 0; nt < 8; ++nt) {
                short8 wwf = *(const short8*)(Ww2 + (size_t)((lane & 15) + 16 * nt) * 32 + (lane >> 4) * 8);
                int d = nt * 16 + (lane & 15);
                float ud = uh_l[w][d];
                float v2 = vw2_l[d];
#pragma unroll
                for (int mt = 0; mt < 4; ++mt) {
                    floatx4 z = {};
                    floatx4 wsa = __builtin_amdgcn_mfma_f32_16x16x32_bf16(pa[mt], wwf, z, 0, 0, 0);
#pragma unroll
                    for (int r = 0; r < 4; ++r)
                        sc[mt][r] += v2 * rcp_f(1.f + exp2f(wsa[r] + ud));
                }
            }
            float mx = -1e30f;
#pragma unroll
            for (int mt = 0; mt < 4; ++mt)
#pragma unroll
                for (int r = 0; r < 4; ++r) {
                    float s = sc[mt][r];
                    s += __shfl_xor(s, 1); s += __shfl_xor(s, 2);
                    s += __shfl_xor(s, 4); s += __shfl_xor(s, 8);
                    s += vwsum;
                    sc[mt][r] = s;
                    mx = fmaxf(mx, s);
                }
            mx = fmaxf(mx, __shfl_xor(mx, 16));
            mx = fmaxf(mx, __shfl_xor(mx, 32));
            float ssum = 0.f;
            float av[4][4];
#pragma unroll
            for (int mt = 0; mt < 4; ++mt)
#pragma unroll
                for (int r = 0; r < 4; ++r) {
                    av[mt][r] = exp2f((sc[mt][r] - mx) * LOG2E);
                    ssum += av[mt][r];
                }
            ssum += __shfl_xor(ssum, 16);
            ssum += __shfl_xor(ssum, 32);
            float rs = rcp_f(ssum);
#pragma unroll
            for (int mt = 0; mt < 4; ++mt) {
                if ((lane & 15) == mt) {
                    float4 fv = make_float4(av[mt][0] * rs, av[mt][1] * rs, av[mt][2] * rs, av[mt][3] * rs);
                    int p0 = mt * 16 + (lane >> 4) * 4;
                    *(float4*)&out_alpha[((size_t)tt * 2048 + b) * 64 + p0] = fv;
                    *(float4*)&al_l[w][p0] = fv;
                }
            }
            // ctx = alpha @ parts, * beta -> xb cols 524:556; x_t -> 512:524
            int k = lane & 31, half = lane >> 5;
            float cp = 0.f;
#pragma unroll
            for (int p = 0; p < 32; ++p) {
                int pp = half * 32 + p;
                cp += al_l[w][pp] * bf2f(parts_bf[(size_t)b * 2048 + pp * 32 + k]);
            }
            cp += __shfl_xor(cp, 32);
            if (half == 0) {
                float beta = sigm(uh_l[w][128 + k]);
                xb[(size_t)b * 576 + 524 + k] = f2bf(cp * beta);
            }
            if (lane < 12)
                xb[(size_t)b * 576 + 512 + lane] = f2bf(label[((size_t)b * 256 + tt) * 12 + lane]);
        }
    };

    // ---------- phase 1: gates GEMM + fused cell ----------
    auto phase1 = [&](const unsigned short* xin, unsigned short* xout) {
        const unsigned short* Ap = xin + (size_t)(mtile * 128 + wm * 64 + (lane & 15)) * 576 + (lane >> 4) * 8;
        const unsigned short* Bb = &Bw[(wn * 32 + (lane & 15)) * 584 + (lane >> 4) * 8];
        floatx4 acc[4][2] = {};
#pragma unroll 3
        for (int kk = 0; kk < 18; ++kk) {
            int k0 = kk * 32;
            short8 b0 = *(const short8*)(Bb + k0);
            short8 b1 = *(const short8*)(Bb + 16 * 584 + k0);
#pragma unroll
            for (int mf = 0; mf < 4; ++mf) {
                short8 a = *(const short8*)(Ap + (size_t)mf * 16 * 576 + k0);
                acc[mf][0] = __builtin_amdgcn_mfma_f32_16x16x32_bf16(a, b0, acc[mf][0], 0, 0, 0);
                acc[mf][1] = __builtin_amdgcn_mfma_f32_16x16x32_bf16(a, b1, acc[mf][1], 0, 0, 0);
            }
        }
        int base = (lane & 48) | (4 * (lane & 3));
        int jl = wn * 8 + (lane & 3);
#pragma unroll
        for (int mf = 0; mf < 4; ++mf)
#pragma unroll
            for (int nf = 0; nf < 2; ++nf) {
#pragma unroll
                for (int r = 0; r < 4; ++r) {
                    float x = acc[mf][nf][r];
                    float g0 = __shfl(x, base + 0);
                    float g1 = __shfl(x, base + 1);
                    float g2 = __shfl(x, base + 2);
                    float g3 = __shfl(x, base + 3);
                    int jj = jl + nf * 4;
                    float gi = g0 + bias_sl[jj];
                    float gf = g1 + bias_sl[32 + jj];
                    float gg = g2 + bias_sl[64 + jj];
                    float go = g3 + bias_sl[96 + jj];
                    int ci = (mf * 2 + nf) * 4 + r;
                    float c2 = sigm(gf) * creg[ci] + sigm(gi) * tanh_f(gg);
                    creg[ci] = c2;
                    float h2 = sigm(go) * tanh_f(c2);
                    if (((lane >> 2) & 3) == 0) {
                        int bg = mtile * 128 + wm * 64 + mf * 16 + (lane >> 4) * 4 + r;
                        xout[(size_t)bg * 576 + ntile * 32 + jj] = f2bf(h2);
                    }
                }
            }
    };

    int bc = 0;
    phase2(0, xh0, false, true);
    gbar(flags, bk, g16, ++bc);
    for (int t = 0; t < 256; ++t) {
        const unsigned short* xin = (t & 1) ? xh1 : xh0;
        unsigned short* xout = (t & 1) ? xh0 : xh1;
        phase1(xin, xout);
        gbar(flags, bk, g16, ++bc);
        phase2(t + 1, xout, true, t < 255);
        if (t < 255) gbar(flags, bk, g16, ++bc);
    }
}

extern "C" void kernel_launch(void* const* d_in, const int* in_sizes, int n_in,
                              void* d_out, int out_size, void* d_ws, size_t ws_size,
                              hipStream_t stream) {
    const float* img   = (const float*)d_in[0];
    const float* label = (const float*)d_in[1];
    const float* Ww    = (const float*)d_in[2];
    const float* Wb    = (const float*)d_in[3];
    const float* Uw    = (const float*)d_in[4];
    const float* Ub    = (const float*)d_in[5];
    const float* vw    = (const float*)d_in[6];
    // d_in[7] = vb (cancels in softmax)
    const float* betaw = (const float*)d_in[8];
    const float* betab = (const float*)d_in[9];
    const float* ihw   = (const float*)d_in[10];
    const float* ihb   = (const float*)d_in[11];
    const float* icw   = (const float*)d_in[12];
    const float* icb   = (const float*)d_in[13];
    const float* Wih   = (const float*)d_in[14];
    const float* Whh   = (const float*)d_in[15];
    const float* bih   = (const float*)d_in[16];
    const float* bhh   = (const float*)d_in[17];
    const float* ow    = (const float*)d_in[18];
    const float* ob    = (const float*)d_in[19];

    char* ws = (char*)d_ws;
    unsigned short* xh0      = (unsigned short*)(ws + OFF_XH0);
    unsigned short* xh1      = (unsigned short*)(ws + OFF_XH1);
    float*          c0       = (float*)(ws + OFF_C0);
    unsigned short* parts_bf = (unsigned short*)(ws + OFF_PARTS);
    unsigned short* Wbig     = (unsigned short*)(ws + OFF_WBIG);
    unsigned short* Wsmall   = (unsigned short*)(ws + OFF_WSMALL);
    unsigned short* Ww2      = (unsigned short*)(ws + OFF_WW2);
    float*          bias     = (float*)(ws + OFF_BIAS);
    float*          avg      = (float*)(ws + OFF_AVG);
    int*            flags    = (int*)(ws + OFF_FLAGS);

    float* out_logits = (float*)d_out;
    float* out_alpha  = out_logits + (size_t)2048 * 256 * 12;

    k_init<<<32, 256, 0, stream>>>(flags);
    k_avg<<<512, 256, 0, stream>>>(img, avg);
    k_prep<<<2048, 256, 0, stream>>>(Whh, Wih, Uw, betaw, Ww, bih, bhh, Wbig, Wsmall, Ww2, bias);
    k_h0c0<<<256, 512, 0, stream>>>(avg, ihw, ihb, icw, icb, xh0, xh1, c0);
    k_parts<<<2048, 256, 0, stream>>>(img, parts_bf);

    k_scan<<<256, 512, 0, stream>>>(xh0, xh1, c0, parts_bf, Wsmall, Wbig, Ww2, bias,
                                    Ub, betab, Wb, vw, label, ow, ob,
                                    out_alpha, out_logits, flags);
}